// Round 1
// baseline (3455.437 us; speedup 1.0000x reference)
//
#include <hip/hip_runtime.h>
#include <math.h>

#define H 256
#define TE 32

// ---------------- K0: y = x (vectorized copy) ----------------
__global__ void copy_kernel(const float* __restrict__ x, float* __restrict__ y, size_t n4) {
    size_t i = (size_t)blockIdx.x * blockDim.x + threadIdx.x;
    size_t stride = (size_t)gridDim.x * blockDim.x;
    const float4* xs = (const float4*)x;
    float4* ys = (float4*)y;
    for (; i < n4; i += stride) ys[i] = xs[i];
}

// ---------------- K1: src_mean[e] = mean of x[he_src[ptr[e]:ptr[e+1]]] ----------------
__global__ __launch_bounds__(256) void seg_mean_kernel(const float* __restrict__ x,
                                                       const int* __restrict__ ptr,
                                                       const int* __restrict__ src,
                                                       float* __restrict__ sm, int E) {
    int e = blockIdx.x;
    if (e >= E) return;
    int j = threadIdx.x;
    int s = ptr[e], t = ptr[e + 1];
    float acc = 0.f;
    for (int i = s; i < t; ++i) {
        acc += x[(size_t)src[i] * H + j];   // src[i] wave-uniform; row read coalesced
    }
    sm[(size_t)e * H + j] = acc * (1.0f / (float)(t - s));
}

// ---------------- K2: msg = src_mean @ W_msg + b_msg (in-place on sm) ----------------
__global__ __launch_bounds__(256) void msg_gemm_kernel(float* __restrict__ sm,
                                                       const float* __restrict__ Wm,
                                                       const float* __restrict__ bm,
                                                       int E) {
    int e0 = blockIdx.x * TE;
    int j = threadIdx.x;
    float acc[TE];
#pragma unroll
    for (int e = 0; e < TE; ++e) acc[e] = 0.f;

    for (int k0 = 0; k0 < H; k0 += 4) {
        float w0 = Wm[(size_t)(k0 + 0) * H + j];
        float w1 = Wm[(size_t)(k0 + 1) * H + j];
        float w2 = Wm[(size_t)(k0 + 2) * H + j];
        float w3 = Wm[(size_t)(k0 + 3) * H + j];
#pragma unroll
        for (int e = 0; e < TE; ++e) {
            int row = e0 + e; if (row >= E) row = E - 1;
            const float4 a = *reinterpret_cast<const float4*>(sm + (size_t)row * H + k0); // uniform -> s_load
            acc[e] = fmaf(a.x, w0, acc[e]);
            acc[e] = fmaf(a.y, w1, acc[e]);
            acc[e] = fmaf(a.z, w2, acc[e]);
            acc[e] = fmaf(a.w, w3, acc[e]);
        }
    }
    float b = bm[j];
    __syncthreads();  // all reads of this block's rows complete before in-place writes
#pragma unroll
    for (int e = 0; e < TE; ++e) {
        int row = e0 + e;
        if (row < E) sm[(size_t)row * H + j] = acc[e] + b;
    }
}

// ---------------- K3: gate = sigmoid([tgt_x, msg] @ W_gate + b_gate); y[tgt] = tgt_x + w*gate*msg ----------------
__global__ __launch_bounds__(256) void gate_upd_kernel(const float* __restrict__ x,
                                                       const float* __restrict__ msg,
                                                       const int* __restrict__ tgt,
                                                       const float* __restrict__ hew,
                                                       const float* __restrict__ Wg,   // [2H, H]
                                                       const float* __restrict__ bg,
                                                       float* __restrict__ y, int E) {
    int e0 = blockIdx.x * TE;
    int j = threadIdx.x;

    int tg[TE];
#pragma unroll
    for (int e = 0; e < TE; ++e) {
        int row = e0 + e; if (row >= E) row = E - 1;
        tg[e] = tgt[row];   // uniform -> SGPR
    }

    float acc[TE];
#pragma unroll
    for (int e = 0; e < TE; ++e) acc[e] = 0.f;

    // tgt_x @ W_gate[0:H]
    for (int k0 = 0; k0 < H; k0 += 4) {
        float w0 = Wg[(size_t)(k0 + 0) * H + j];
        float w1 = Wg[(size_t)(k0 + 1) * H + j];
        float w2 = Wg[(size_t)(k0 + 2) * H + j];
        float w3 = Wg[(size_t)(k0 + 3) * H + j];
#pragma unroll
        for (int e = 0; e < TE; ++e) {
            const float4 a = *reinterpret_cast<const float4*>(x + (size_t)tg[e] * H + k0);
            acc[e] = fmaf(a.x, w0, acc[e]);
            acc[e] = fmaf(a.y, w1, acc[e]);
            acc[e] = fmaf(a.z, w2, acc[e]);
            acc[e] = fmaf(a.w, w3, acc[e]);
        }
    }
    // msg @ W_gate[H:2H]
    for (int k0 = 0; k0 < H; k0 += 4) {
        float w0 = Wg[(size_t)(H + k0 + 0) * H + j];
        float w1 = Wg[(size_t)(H + k0 + 1) * H + j];
        float w2 = Wg[(size_t)(H + k0 + 2) * H + j];
        float w3 = Wg[(size_t)(H + k0 + 3) * H + j];
#pragma unroll
        for (int e = 0; e < TE; ++e) {
            int row = e0 + e; if (row >= E) row = E - 1;
            const float4 a = *reinterpret_cast<const float4*>(msg + (size_t)row * H + k0);
            acc[e] = fmaf(a.x, w0, acc[e]);
            acc[e] = fmaf(a.y, w1, acc[e]);
            acc[e] = fmaf(a.z, w2, acc[e]);
            acc[e] = fmaf(a.w, w3, acc[e]);
        }
    }

    float b = bg[j];
#pragma unroll
    for (int e = 0; e < TE; ++e) {
        int row = e0 + e;
        if (row >= E) break;
        float z = acc[e] + b;
        float g = 1.f / (1.f + __expf(-z));
        float tx = x[(size_t)tg[e] * H + j];
        float m  = msg[(size_t)row * H + j];
        float u  = tx + hew[row] * g * m;
        y[(size_t)tg[e] * H + j] = u;
    }
}

// ---------------- K4: out = clip(y @ W_upd + b_upd, 0, 1)  (in-place on y == d_out) ----------------
__global__ __launch_bounds__(256) void out_gemm_kernel(float* __restrict__ y,
                                                       const float* __restrict__ Wu,
                                                       const float* __restrict__ bu,
                                                       int R) {
    int r0 = blockIdx.x * TE;
    int j = threadIdx.x;
    float acc[TE];
#pragma unroll
    for (int e = 0; e < TE; ++e) acc[e] = 0.f;

    for (int k0 = 0; k0 < H; k0 += 4) {
        float w0 = Wu[(size_t)(k0 + 0) * H + j];
        float w1 = Wu[(size_t)(k0 + 1) * H + j];
        float w2 = Wu[(size_t)(k0 + 2) * H + j];
        float w3 = Wu[(size_t)(k0 + 3) * H + j];
#pragma unroll
        for (int e = 0; e < TE; ++e) {
            int row = r0 + e; if (row >= R) row = R - 1;
            const float4 a = *reinterpret_cast<const float4*>(y + (size_t)row * H + k0);
            acc[e] = fmaf(a.x, w0, acc[e]);
            acc[e] = fmaf(a.y, w1, acc[e]);
            acc[e] = fmaf(a.z, w2, acc[e]);
            acc[e] = fmaf(a.w, w3, acc[e]);
        }
    }
    float b = bu[j];
    __syncthreads();  // reads done before in-place writes
#pragma unroll
    for (int e = 0; e < TE; ++e) {
        int row = r0 + e;
        if (row < R) {
            float v = acc[e] + b;
            v = fminf(fmaxf(v, 0.f), 1.f);
            y[(size_t)row * H + j] = v;
        }
    }
}

extern "C" void kernel_launch(void* const* d_in, const int* in_sizes, int n_in,
                              void* d_out, int out_size, void* d_ws, size_t ws_size,
                              hipStream_t stream) {
    const float* x      = (const float*)d_in[0];
    const int*   he_ptr = (const int*)d_in[1];
    const int*   he_src = (const int*)d_in[2];
    const int*   he_tgt = (const int*)d_in[3];
    const float* he_w   = (const float*)d_in[4];
    const float* W_msg  = (const float*)d_in[5];
    const float* b_msg  = (const float*)d_in[6];
    const float* W_gate = (const float*)d_in[7];
    const float* b_gate = (const float*)d_in[8];
    const float* W_upd  = (const float*)d_in[9];
    const float* b_upd  = (const float*)d_in[10];

    const int E = in_sizes[3];
    const int R = in_sizes[0] / H;

    float* sm = (float*)d_ws;      // E*H floats: src_mean, then msg (in-place)
    float* y  = (float*)d_out;     // R*H floats: y = x with tgt rows replaced, then final out (in-place)

    size_t n4 = (size_t)R * H / 4;
    copy_kernel<<<2048, 256, 0, stream>>>(x, y, n4);
    seg_mean_kernel<<<E, 256, 0, stream>>>(x, he_ptr, he_src, sm, E);
    msg_gemm_kernel<<<(E + TE - 1) / TE, 256, 0, stream>>>(sm, W_msg, b_msg, E);
    gate_upd_kernel<<<(E + TE - 1) / TE, 256, 0, stream>>>(x, sm, he_tgt, he_w, W_gate, b_gate, y, E);
    out_gemm_kernel<<<(R + TE - 1) / TE, 256, 0, stream>>>(y, W_upd, b_upd, R);
}

// Round 2
// 583.730 us; speedup vs baseline: 5.9196x; 5.9196x over previous
//
#include <hip/hip_runtime.h>
#include <math.h>

#define H 256

typedef __attribute__((ext_vector_type(8))) short short8;
typedef __attribute__((ext_vector_type(4))) float f32x4;
typedef __attribute__((ext_vector_type(4))) int int4v;
typedef unsigned short ushort_t;

__device__ __forceinline__ float bf2f(unsigned short u) {
    union { unsigned int i; float f; } v; v.i = ((unsigned int)u) << 16; return v.f;
}
__device__ __forceinline__ unsigned short f2bf(float f) {
    union { float f; unsigned int i; } v; v.f = f;
    unsigned int r = v.i + 0x7FFFu + ((v.i >> 16) & 1u);   // round-to-nearest-even
    return (unsigned short)(r >> 16);
}
__device__ __forceinline__ void glds16(const void* g, void* l) {
    __builtin_amdgcn_global_load_lds((const __attribute__((address_space(1))) void*)g,
                                     (__attribute__((address_space(3))) void*)l, 16, 0, 0);
}
__device__ __forceinline__ int4v pack_f32x8_bf16(const float* p) {
    float4 f0 = *(const float4*)(p);
    float4 f1 = *(const float4*)(p + 4);
    int4v d;
    d.x = (int)((unsigned)f2bf(f0.x) | ((unsigned)f2bf(f0.y) << 16));
    d.y = (int)((unsigned)f2bf(f0.z) | ((unsigned)f2bf(f0.w) << 16));
    d.z = (int)((unsigned)f2bf(f1.x) | ((unsigned)f2bf(f1.y) << 16));
    d.w = (int)((unsigned)f2bf(f1.z) | ((unsigned)f2bf(f1.w) << 16));
    return d;
}

// ---------------- small prep kernels ----------------
__global__ void prep_weights(const float* __restrict__ Wm, const float* __restrict__ Wg,
                             const float* __restrict__ Wu,
                             ushort_t* __restrict__ Wmt, ushort_t* __restrict__ Wgt,
                             ushort_t* __restrict__ Wut) {
    int idx = blockIdx.x * 256 + threadIdx.x;
    if (idx < 65536) {                       // [256][256] -> [n][k]
        int n = idx >> 8, k = idx & 255;
        Wmt[idx] = f2bf(Wm[(size_t)k * 256 + n]);
        Wut[idx] = f2bf(Wu[(size_t)k * 256 + n]);
    }
    if (idx < 131072) {                      // [512][256] -> [n][512 k]
        int n = idx >> 9, k = idx & 511;
        Wgt[idx] = f2bf(Wg[(size_t)k * 256 + n]);
    }
}

__global__ void imap_init(int* __restrict__ imap, int R) {
    int r = blockIdx.x * 256 + threadIdx.x;
    if (r < R) imap[r] = -1;
}
__global__ void imap_scatter(const int* __restrict__ tgt, int* __restrict__ imap, int E) {
    int e = blockIdx.x * 256 + threadIdx.x;
    if (e < E) imap[tgt[e]] = e;
}

// ---------------- seg mean -> bf16 ----------------
__global__ __launch_bounds__(256) void seg_mean_kernel(const float* __restrict__ x,
                                                       const int* __restrict__ ptr,
                                                       const int* __restrict__ src,
                                                       ushort_t* __restrict__ smb, int E) {
    int e = blockIdx.x;
    int j = threadIdx.x;
    int s = ptr[e], t = ptr[e + 1];
    float a = 0.f;
    for (int i = s; i < t; ++i) a += x[(size_t)src[i] * H + j];
    smb[(size_t)e * H + j] = f2bf(a * (1.f / (float)(t - s)));
}

// ---------------- unified MFMA GEMM ----------------
// C[M,256] = A[M,KTOT] @ W[KTOT,256] (+epilogue). Tile 128x128, BK=32, 4 waves.
// MODE 0: A = Abf (bf16 rows, global_load_lds). Epi: bf16(z+bias) -> OutB.
// MODE 1: A row e = [bf16(x[tgt[e]]) | msgb[e]] (KTOT=512, reg-staged).
//         Epi: g=sigmoid(z+bias); u = x[tgt[e]][col] + hew[e]*g*msg; OutB=bf16(u).
// MODE 2: A row r = imap[r]>=0 ? updb[imap[r]] : bf16(x[r]) (reg-staged).
//         Epi: OutF = clip(z+bias,0,1) fp32.
template<int MODE, int KTOT>
__global__ __launch_bounds__(256) void mfma_gemm(
    const ushort_t* __restrict__ Abf,
    const float* __restrict__ Xf,
    const ushort_t* __restrict__ Aux,
    const int* __restrict__ Idx,
    const float* __restrict__ Hew,
    const ushort_t* __restrict__ Wt,     // [256][KTOT] bf16 (pre-transposed)
    const float* __restrict__ Bias,      // [256] fp32
    ushort_t* __restrict__ OutB,
    float* __restrict__ OutF,
    int M)
{
    constexpr int NT = KTOT / 32;
    const int m0 = blockIdx.x * 128;
    const int c0 = blockIdx.y * 128;
    const int tid = threadIdx.x;
    const int wv = tid >> 6;
    const int lane = tid & 63;
    const int wr = wv >> 1, wc = wv & 1;

    __shared__ __align__(16) ushort_t As[2][128 * 32];
    __shared__ __align__(16) ushort_t Bs[2][128 * 32];

    f32x4 acc[4][4];
#pragma unroll
    for (int i = 0; i < 4; ++i)
#pragma unroll
        for (int j = 0; j < 4; ++j) acc[i][j] = (f32x4){0.f, 0.f, 0.f, 0.f};

    const int ch0 = wv * 64 + lane;     // chunk ids: LDS byte = ch*16 (wave-uniform base + lane*16)
    const int ch1 = ch0 + 256;

    auto stageB = [&](int buf, int k0) {
#pragma unroll
        for (int c = 0; c < 2; ++c) {
            int ch = c ? ch1 : ch0;
            int col = ch >> 2, sl = ch & 3, cc = sl ^ (col & 3);   // XOR swizzle (source side)
            glds16(Wt + (size_t)(c0 + col) * KTOT + (k0 + cc * 8),
                   (char*)(&Bs[buf][0]) + ch * 16);
        }
    };

    auto stageA = [&](int buf, int k0) {
#pragma unroll
        for (int c = 0; c < 2; ++c) {
            int ch = c ? ch1 : ch0;
            int row = ch >> 2, sl = ch & 3, cc = sl ^ (row & 3);
            int kg = k0 + cc * 8;
            int r = m0 + row; if (r > M - 1) r = M - 1;
            if constexpr (MODE == 0) {
                glds16(Abf + (size_t)r * KTOT + kg, (char*)(&As[buf][0]) + ch * 16);
            } else {
                int4v d;
                if constexpr (MODE == 1) {
                    if (k0 < 256) {
                        int tr = Idx[r];
                        d = pack_f32x8_bf16(Xf + (size_t)tr * 256 + kg);
                    } else {
                        d = *(const int4v*)(Aux + (size_t)r * 256 + (kg - 256));
                    }
                } else {
                    int e = Idx[r];
                    if (e >= 0) d = *(const int4v*)(Aux + (size_t)e * 256 + kg);
                    else        d = pack_f32x8_bf16(Xf + (size_t)r * 256 + kg);
                }
                *(int4v*)((char*)(&As[buf][0]) + ch * 16) = d;
            }
        }
    };

    auto compute = [&](int buf) {
        short8 a[4], b[4];
#pragma unroll
        for (int fm = 0; fm < 4; ++fm) {
            int row = wr * 64 + fm * 16 + (lane & 15);
            int byte = (row * 4 + ((lane >> 4) ^ (row & 3))) * 16;   // XOR swizzle (read side)
            a[fm] = *(const short8*)((const char*)(&As[buf][0]) + byte);
        }
#pragma unroll
        for (int fn = 0; fn < 4; ++fn) {
            int col = wc * 64 + fn * 16 + (lane & 15);
            int byte = (col * 4 + ((lane >> 4) ^ (col & 3))) * 16;
            b[fn] = *(const short8*)((const char*)(&Bs[buf][0]) + byte);
        }
#pragma unroll
        for (int fm = 0; fm < 4; ++fm)
#pragma unroll
            for (int fn = 0; fn < 4; ++fn)
                acc[fm][fn] = __builtin_amdgcn_mfma_f32_16x16x32_bf16(a[fm], b[fn], acc[fm][fn], 0, 0, 0);
    };

    stageA(0, 0); stageB(0, 0);
    __syncthreads();
    for (int kt = 0; kt < NT; ++kt) {
        if (kt + 1 < NT) { stageA((kt + 1) & 1, (kt + 1) * 32); stageB((kt + 1) & 1, (kt + 1) * 32); }
        compute(kt & 1);
        __syncthreads();
    }

    // epilogue: C/D layout col=lane&15, row=(lane>>4)*4+i
#pragma unroll
    for (int fm = 0; fm < 4; ++fm) {
        int rbase = m0 + wr * 64 + fm * 16 + (lane >> 4) * 4;
#pragma unroll
        for (int fn = 0; fn < 4; ++fn) {
            int col = c0 + wc * 64 + fn * 16 + (lane & 15);
            float bia = Bias[col];
            f32x4 v = acc[fm][fn];
#pragma unroll
            for (int i = 0; i < 4; ++i) {
                int rg = rbase + i;
                if (rg < M) {
                    float z = v[i] + bia;
                    if constexpr (MODE == 0) {
                        OutB[(size_t)rg * 256 + col] = f2bf(z);
                    } else if constexpr (MODE == 1) {
                        float g = 1.f / (1.f + __expf(-z));
                        int tr = Idx[rg];
                        float tx = Xf[(size_t)tr * 256 + col];
                        float m = bf2f(Aux[(size_t)rg * 256 + col]);
                        float u = tx + Hew[rg] * g * m;
                        OutB[(size_t)rg * 256 + col] = f2bf(u);
                    } else {
                        float u = fminf(fmaxf(z, 0.f), 1.f);
                        OutF[(size_t)rg * 256 + col] = u;
                    }
                }
            }
        }
    }
}

extern "C" void kernel_launch(void* const* d_in, const int* in_sizes, int n_in,
                              void* d_out, int out_size, void* d_ws, size_t ws_size,
                              hipStream_t stream) {
    const float* x      = (const float*)d_in[0];
    const int*   he_ptr = (const int*)d_in[1];
    const int*   he_src = (const int*)d_in[2];
    const int*   he_tgt = (const int*)d_in[3];
    const float* he_w   = (const float*)d_in[4];
    const float* W_msg  = (const float*)d_in[5];
    const float* b_msg  = (const float*)d_in[6];
    const float* W_gate = (const float*)d_in[7];
    const float* b_gate = (const float*)d_in[8];
    const float* W_upd  = (const float*)d_in[9];
    const float* b_upd  = (const float*)d_in[10];

    const int E = in_sizes[3];
    const int R = in_sizes[0] / H;

    // workspace layout (~104 MB)
    char* ws = (char*)d_ws;
    ushort_t* buf0 = (ushort_t*)ws;                               // E*256 bf16: smb, later updb
    ushort_t* buf1 = (ushort_t*)(ws + (size_t)E * H * 2);         // E*256 bf16: msgb
    int*      imap = (int*)(ws + (size_t)E * H * 4);              // R int32
    ushort_t* Wmt  = (ushort_t*)((char*)imap + (size_t)R * 4);    // 256*256 bf16
    ushort_t* Wgt  = Wmt + 256 * 256;                             // 256*512 bf16
    ushort_t* Wut  = Wgt + 256 * 512;                             // 256*256 bf16

    prep_weights<<<512, 256, 0, stream>>>(W_msg, W_gate, W_upd, Wmt, Wgt, Wut);
    imap_init<<<(R + 255) / 256, 256, 0, stream>>>(imap, R);
    imap_scatter<<<(E + 255) / 256, 256, 0, stream>>>(he_tgt, imap, E);
    seg_mean_kernel<<<E, 256, 0, stream>>>(x, he_ptr, he_src, buf0, E);

    dim3 gE((E + 127) / 128, 2);
    dim3 gR((R + 127) / 128, 2);
    // msg = smb @ Wm + b   (buf0 -> buf1)
    mfma_gemm<0, 256><<<gE, 256, 0, stream>>>(buf0, nullptr, nullptr, nullptr, nullptr,
                                              Wmt, b_msg, buf1, nullptr, E);
    // gate + gated residual (reads x,buf1 -> writes updb into buf0)
    mfma_gemm<1, 512><<<gE, 256, 0, stream>>>(nullptr, x, buf1, he_tgt, he_w,
                                              Wgt, b_gate, buf0, nullptr, E);
    // out = clip(y @ Wu + b) with y rows from x or updb(buf0) via imap -> d_out fp32
    mfma_gemm<2, 256><<<gR, 256, 0, stream>>>(nullptr, x, buf0, imap, nullptr,
                                              Wut, b_upd, nullptr, (float*)d_out, R);
}

// Round 3
// 422.121 us; speedup vs baseline: 8.1859x; 1.3829x over previous
//
#include <hip/hip_runtime.h>
#include <math.h>

#define H 256

typedef __attribute__((ext_vector_type(8))) short short8;
typedef __attribute__((ext_vector_type(4))) float f32x4;
typedef __attribute__((ext_vector_type(4))) int int4v;
typedef __attribute__((ext_vector_type(2))) unsigned int uint2v;
typedef unsigned short ushort_t;

__device__ __forceinline__ float bf2f(unsigned short u) {
    union { unsigned int i; float f; } v; v.i = ((unsigned int)u) << 16; return v.f;
}
__device__ __forceinline__ unsigned short f2bf(float f) {
    union { float f; unsigned int i; } v; v.f = f;
    unsigned int r = v.i + 0x7FFFu + ((v.i >> 16) & 1u);   // RNE
    return (unsigned short)(r >> 16);
}
__device__ __forceinline__ void glds16(const void* g, void* l) {
    __builtin_amdgcn_global_load_lds((const __attribute__((address_space(1))) void*)g,
                                     (__attribute__((address_space(3))) void*)l, 16, 0, 0);
}
__device__ __forceinline__ int4v pack_f32x8_bf16(const float* p) {
    float4 f0 = *(const float4*)(p);
    float4 f1 = *(const float4*)(p + 4);
    int4v d;
    d.x = (int)((unsigned)f2bf(f0.x) | ((unsigned)f2bf(f0.y) << 16));
    d.y = (int)((unsigned)f2bf(f0.z) | ((unsigned)f2bf(f0.w) << 16));
    d.z = (int)((unsigned)f2bf(f1.x) | ((unsigned)f2bf(f1.y) << 16));
    d.w = (int)((unsigned)f2bf(f1.z) | ((unsigned)f2bf(f1.w) << 16));
    return d;
}

// ---------------- prep ----------------
__global__ void prep_weights(const float* __restrict__ Wm, const float* __restrict__ Wg,
                             const float* __restrict__ Wu,
                             ushort_t* __restrict__ Wmt, ushort_t* __restrict__ Wgt,
                             ushort_t* __restrict__ Wut) {
    int idx = blockIdx.x * 256 + threadIdx.x;
    if (idx < 65536) {                       // [256][256] -> [n][k]
        int n = idx >> 8, k = idx & 255;
        Wmt[idx] = f2bf(Wm[(size_t)k * 256 + n]);
        Wut[idx] = f2bf(Wu[(size_t)k * 256 + n]);
    }
    if (idx < 131072) {                      // [512][256] -> [n][512 k]
        int n = idx >> 9, k = idx & 511;
        Wgt[idx] = f2bf(Wg[(size_t)k * 256 + n]);
    }
}

__global__ void imap_init(int* __restrict__ imap, int R) {
    int r = blockIdx.x * 256 + threadIdx.x;
    if (r < R) imap[r] = -1;
}
__global__ void imap_scatter(const int* __restrict__ tgt, int* __restrict__ imap, int E) {
    int e = blockIdx.x * 256 + threadIdx.x;
    if (e < E) imap[tgt[e]] = e;
}

// ---------------- x -> bf16 copy ----------------
__global__ void conv_bf16(const float* __restrict__ x, ushort_t* __restrict__ yb, size_t n8) {
    size_t i = (size_t)blockIdx.x * blockDim.x + threadIdx.x;
    size_t stride = (size_t)gridDim.x * blockDim.x;
    for (; i < n8; i += stride)
        *(int4v*)(yb + i * 8) = pack_f32x8_bf16(x + i * 8);
}

// ---------------- segment mean: wave-per-edge, unroll-4 ----------------
__global__ __launch_bounds__(256) void seg_mean_bf16(const ushort_t* __restrict__ yb,
                                                     const int* __restrict__ ptr,
                                                     const int* __restrict__ src,
                                                     ushort_t* __restrict__ smb, int E) {
    int e = blockIdx.x * 4 + (threadIdx.x >> 6);
    if (e >= E) return;
    int lane = threadIdx.x & 63;
    int s = ptr[e], t = ptr[e + 1];
    float a0 = 0.f, a1 = 0.f, a2 = 0.f, a3 = 0.f;
    int i = s;
    for (; i + 4 <= t; i += 4) {
        uint2v v0 = *(const uint2v*)(yb + (size_t)src[i + 0] * H + lane * 4);
        uint2v v1 = *(const uint2v*)(yb + (size_t)src[i + 1] * H + lane * 4);
        uint2v v2 = *(const uint2v*)(yb + (size_t)src[i + 2] * H + lane * 4);
        uint2v v3 = *(const uint2v*)(yb + (size_t)src[i + 3] * H + lane * 4);
        a0 += bf2f(v0.x & 0xffff) + bf2f(v1.x & 0xffff) + bf2f(v2.x & 0xffff) + bf2f(v3.x & 0xffff);
        a1 += bf2f(v0.x >> 16)    + bf2f(v1.x >> 16)    + bf2f(v2.x >> 16)    + bf2f(v3.x >> 16);
        a2 += bf2f(v0.y & 0xffff) + bf2f(v1.y & 0xffff) + bf2f(v2.y & 0xffff) + bf2f(v3.y & 0xffff);
        a3 += bf2f(v0.y >> 16)    + bf2f(v1.y >> 16)    + bf2f(v2.y >> 16)    + bf2f(v3.y >> 16);
    }
    for (; i < t; ++i) {
        uint2v v = *(const uint2v*)(yb + (size_t)src[i] * H + lane * 4);
        a0 += bf2f(v.x & 0xffff); a1 += bf2f(v.x >> 16);
        a2 += bf2f(v.y & 0xffff); a3 += bf2f(v.y >> 16);
    }
    float inv = 1.f / (float)(t - s);
    uint2v o;
    o.x = (unsigned)f2bf(a0 * inv) | ((unsigned)f2bf(a1 * inv) << 16);
    o.y = (unsigned)f2bf(a2 * inv) | ((unsigned)f2bf(a3 * inv) << 16);
    *(uint2v*)(smb + (size_t)e * H + lane * 4) = o;
}

// fallback: fp32 gather (small-ws path)
__global__ __launch_bounds__(256) void seg_mean_f32w(const float* __restrict__ x,
                                                     const int* __restrict__ ptr,
                                                     const int* __restrict__ src,
                                                     ushort_t* __restrict__ smb, int E) {
    int e = blockIdx.x * 4 + (threadIdx.x >> 6);
    if (e >= E) return;
    int lane = threadIdx.x & 63;
    int s = ptr[e], t = ptr[e + 1];
    float a0 = 0.f, a1 = 0.f, a2 = 0.f, a3 = 0.f;
    int i = s;
    for (; i + 4 <= t; i += 4) {
        float4 v0 = *(const float4*)(x + (size_t)src[i + 0] * H + lane * 4);
        float4 v1 = *(const float4*)(x + (size_t)src[i + 1] * H + lane * 4);
        float4 v2 = *(const float4*)(x + (size_t)src[i + 2] * H + lane * 4);
        float4 v3 = *(const float4*)(x + (size_t)src[i + 3] * H + lane * 4);
        a0 += v0.x + v1.x + v2.x + v3.x;
        a1 += v0.y + v1.y + v2.y + v3.y;
        a2 += v0.z + v1.z + v2.z + v3.z;
        a3 += v0.w + v1.w + v2.w + v3.w;
    }
    for (; i < t; ++i) {
        float4 v = *(const float4*)(x + (size_t)src[i] * H + lane * 4);
        a0 += v.x; a1 += v.y; a2 += v.z; a3 += v.w;
    }
    float inv = 1.f / (float)(t - s);
    uint2v o;
    o.x = (unsigned)f2bf(a0 * inv) | ((unsigned)f2bf(a1 * inv) << 16);
    o.y = (unsigned)f2bf(a2 * inv) | ((unsigned)f2bf(a3 * inv) << 16);
    *(uint2v*)(smb + (size_t)e * H + lane * 4) = o;
}

// ---------------- unified MFMA GEMM ----------------
// C[M,256] = A[M,KTOT] @ W[KTOT,256] (+epilogue). Tile 128x128, BK=32, 4 waves.
// MODE 0: A = Abf (linear bf16, global_load_lds). Epi: OutB = bf16(z+bias).
// MODE 1: A row e = [x[tgt[e]] | msg[e]] (KTOT=512, reg-staged).
//         Epi: g=sigmoid(z+bias); u = tx + hew*g*m; OutB = bf16(u).
// MODE 2: A row r = imap[r]>=0 ? upd[imap[r]] : x[r] (reg-staged).
//         Epi: OutF = clip(z+bias,0,1) fp32.
// XB: x rows come from Xb (bf16) instead of Xf (fp32 + convert).
template<int MODE, int KTOT, bool XB>
__global__ __launch_bounds__(256) void mfma_gemm(
    const ushort_t* __restrict__ Abf,
    const float* __restrict__ Xf,
    const ushort_t* __restrict__ Xb,
    const ushort_t* __restrict__ Aux,
    const int* __restrict__ Idx,
    const float* __restrict__ Hew,
    const ushort_t* __restrict__ Wt,     // [256][KTOT] bf16 (pre-transposed)
    const float* __restrict__ Bias,      // [256] fp32
    ushort_t* __restrict__ OutB,
    float* __restrict__ OutF,
    int M)
{
    constexpr int NT = KTOT / 32;
    const int m0 = blockIdx.x * 128;
    const int c0 = blockIdx.y * 128;
    const int tid = threadIdx.x;
    const int wv = tid >> 6;
    const int lane = tid & 63;
    const int wr = wv >> 1, wc = wv & 1;

    __shared__ __align__(16) ushort_t As[2][128 * 32];
    __shared__ __align__(16) ushort_t Bs[2][128 * 32];

    f32x4 acc[4][4];
#pragma unroll
    for (int i = 0; i < 4; ++i)
#pragma unroll
        for (int j = 0; j < 4; ++j) acc[i][j] = (f32x4){0.f, 0.f, 0.f, 0.f};

    const int ch0 = wv * 64 + lane;     // LDS chunk id; byte = ch*16
    const int ch1 = ch0 + 256;

    auto stageB = [&](int buf, int k0) {
#pragma unroll
        for (int c = 0; c < 2; ++c) {
            int ch = c ? ch1 : ch0;
            int col = ch >> 2, sl = ch & 3, cc = sl ^ (col & 3);   // XOR swizzle (source side)
            glds16(Wt + (size_t)(c0 + col) * KTOT + (k0 + cc * 8),
                   (char*)(&Bs[buf][0]) + ch * 16);
        }
    };

    auto stageA = [&](int buf, int k0) {
#pragma unroll
        for (int c = 0; c < 2; ++c) {
            int ch = c ? ch1 : ch0;
            int row = ch >> 2, sl = ch & 3, cc = sl ^ (row & 3);
            int kg = k0 + cc * 8;
            int r = m0 + row; if (r > M - 1) r = M - 1;
            if constexpr (MODE == 0) {
                glds16(Abf + (size_t)r * KTOT + kg, (char*)(&As[buf][0]) + ch * 16);
            } else {
                int4v d;
                if constexpr (MODE == 1) {
                    if (k0 < 256) {
                        int tr = Idx[r];
                        if constexpr (XB) d = *(const int4v*)(Xb + (size_t)tr * 256 + kg);
                        else              d = pack_f32x8_bf16(Xf + (size_t)tr * 256 + kg);
                    } else {
                        d = *(const int4v*)(Aux + (size_t)r * 256 + (kg - 256));
                    }
                } else {
                    int e = Idx[r];
                    if (e >= 0) d = *(const int4v*)(Aux + (size_t)e * 256 + kg);
                    else if constexpr (XB) d = *(const int4v*)(Xb + (size_t)r * 256 + kg);
                    else d = pack_f32x8_bf16(Xf + (size_t)r * 256 + kg);
                }
                *(int4v*)((char*)(&As[buf][0]) + ch * 16) = d;
            }
        }
    };

    auto compute = [&](int buf) {
        short8 a[4], b[4];
#pragma unroll
        for (int fm = 0; fm < 4; ++fm) {
            int row = wr * 64 + fm * 16 + (lane & 15);
            int byte = (row * 4 + ((lane >> 4) ^ (row & 3))) * 16;   // XOR swizzle (read side)
            a[fm] = *(const short8*)((const char*)(&As[buf][0]) + byte);
        }
#pragma unroll
        for (int fn = 0; fn < 4; ++fn) {
            int col = wc * 64 + fn * 16 + (lane & 15);
            int byte = (col * 4 + ((lane >> 4) ^ (col & 3))) * 16;
            b[fn] = *(const short8*)((const char*)(&Bs[buf][0]) + byte);
        }
#pragma unroll
        for (int fm = 0; fm < 4; ++fm)
#pragma unroll
            for (int fn = 0; fn < 4; ++fn)
                acc[fm][fn] = __builtin_amdgcn_mfma_f32_16x16x32_bf16(a[fm], b[fn], acc[fm][fn], 0, 0, 0);
    };

    stageA(0, 0); stageB(0, 0);
    __syncthreads();
    for (int kt = 0; kt < NT; ++kt) {
        if (kt + 1 < NT) { stageA((kt + 1) & 1, (kt + 1) * 32); stageB((kt + 1) & 1, (kt + 1) * 32); }
        compute(kt & 1);
        __syncthreads();
    }

    // epilogue: C/D layout col=lane&15, row=(lane>>4)*4+i
#pragma unroll
    for (int fm = 0; fm < 4; ++fm) {
        int rbase = m0 + wr * 64 + fm * 16 + (lane >> 4) * 4;
#pragma unroll
        for (int fn = 0; fn < 4; ++fn) {
            int col = c0 + wc * 64 + fn * 16 + (lane & 15);
            float bia = Bias[col];
            f32x4 v = acc[fm][fn];
#pragma unroll
            for (int i = 0; i < 4; ++i) {
                int rg = rbase + i;
                if (rg < M) {
                    float z = v[i] + bia;
                    if constexpr (MODE == 0) {
                        OutB[(size_t)rg * 256 + col] = f2bf(z);
                    } else if constexpr (MODE == 1) {
                        float g = 1.f / (1.f + __expf(-z));
                        int tr = Idx[rg];
                        float tx;
                        if constexpr (XB) tx = bf2f(Xb[(size_t)tr * 256 + col]);
                        else              tx = Xf[(size_t)tr * 256 + col];
                        float m = bf2f(Aux[(size_t)rg * 256 + col]);
                        float u = tx + Hew[rg] * g * m;
                        OutB[(size_t)rg * 256 + col] = f2bf(u);
                    } else {
                        OutF[(size_t)rg * 256 + col] = fminf(fmaxf(z, 0.f), 1.f);
                    }
                }
            }
        }
    }
}

extern "C" void kernel_launch(void* const* d_in, const int* in_sizes, int n_in,
                              void* d_out, int out_size, void* d_ws, size_t ws_size,
                              hipStream_t stream) {
    const float* x      = (const float*)d_in[0];
    const int*   he_ptr = (const int*)d_in[1];
    const int*   he_src = (const int*)d_in[2];
    const int*   he_tgt = (const int*)d_in[3];
    const float* he_w   = (const float*)d_in[4];
    const float* W_msg  = (const float*)d_in[5];
    const float* b_msg  = (const float*)d_in[6];
    const float* W_gate = (const float*)d_in[7];
    const float* b_gate = (const float*)d_in[8];
    const float* W_upd  = (const float*)d_in[9];
    const float* b_upd  = (const float*)d_in[10];

    const int E = in_sizes[3];
    const int R = in_sizes[0] / H;

    const size_t wbytes = (size_t)(65536 + 131072 + 65536) * 2;
    const size_t needA = (size_t)R * H * 2 + (size_t)E * H * 2 * 2 + (size_t)R * 4 + wbytes;
    const bool bigws = ws_size >= needA;

    dim3 gE((E + 127) / 128, 2);
    dim3 gR((R + 127) / 128, 2);

    if (bigws) {
        char* ws = (char*)d_ws;
        ushort_t* yb   = (ushort_t*)ws;                                // R*256 bf16(x)
        ushort_t* buf0 = yb + (size_t)R * H;                           // E*256: smb, later updb
        ushort_t* buf1 = buf0 + (size_t)E * H;                         // E*256: msgb
        int*      imap = (int*)(buf1 + (size_t)E * H);                 // R
        ushort_t* Wmt  = (ushort_t*)((char*)imap + (size_t)R * 4);
        ushort_t* Wgt  = Wmt + 256 * 256;
        ushort_t* Wut  = Wgt + 256 * 512;

        prep_weights<<<512, 256, 0, stream>>>(W_msg, W_gate, W_upd, Wmt, Wgt, Wut);
        imap_init<<<(R + 255) / 256, 256, 0, stream>>>(imap, R);
        imap_scatter<<<(E + 255) / 256, 256, 0, stream>>>(he_tgt, imap, E);
        conv_bf16<<<2048, 256, 0, stream>>>(x, yb, (size_t)R * H / 8);
        seg_mean_bf16<<<(E + 3) / 4, 256, 0, stream>>>(yb, he_ptr, he_src, buf0, E);

        mfma_gemm<0, 256, true><<<gE, 256, 0, stream>>>(buf0, nullptr, yb, nullptr, nullptr, nullptr,
                                                        Wmt, b_msg, buf1, nullptr, E);
        mfma_gemm<1, 512, true><<<gE, 256, 0, stream>>>(nullptr, nullptr, yb, buf1, he_tgt, he_w,
                                                        Wgt, b_gate, buf0, nullptr, E);
        mfma_gemm<2, 256, true><<<gR, 256, 0, stream>>>(nullptr, nullptr, yb, buf0, imap, nullptr,
                                                        Wut, b_upd, nullptr, (float*)d_out, R);
    } else {
        char* ws = (char*)d_ws;
        ushort_t* buf0 = (ushort_t*)ws;
        ushort_t* buf1 = buf0 + (size_t)E * H;
        int*      imap = (int*)(buf1 + (size_t)E * H);
        ushort_t* Wmt  = (ushort_t*)((char*)imap + (size_t)R * 4);
        ushort_t* Wgt  = Wmt + 256 * 256;
        ushort_t* Wut  = Wgt + 256 * 512;

        prep_weights<<<512, 256, 0, stream>>>(W_msg, W_gate, W_upd, Wmt, Wgt, Wut);
        imap_init<<<(R + 255) / 256, 256, 0, stream>>>(imap, R);
        imap_scatter<<<(E + 255) / 256, 256, 0, stream>>>(he_tgt, imap, E);
        seg_mean_f32w<<<(E + 3) / 4, 256, 0, stream>>>(x, he_ptr, he_src, buf0, E);

        mfma_gemm<0, 256, false><<<gE, 256, 0, stream>>>(buf0, nullptr, nullptr, nullptr, nullptr, nullptr,
                                                         Wmt, b_msg, buf1, nullptr, E);
        mfma_gemm<1, 512, false><<<gE, 256, 0, stream>>>(nullptr, x, nullptr, buf1, he_tgt, he_w,
                                                         Wgt, b_gate, buf0, nullptr, E);
        mfma_gemm<2, 256, false><<<gR, 256, 0, stream>>>(nullptr, x, nullptr, buf0, imap, nullptr,
                                                         Wut, b_upd, nullptr, (float*)d_out, R);
    }
}